// Round 2
// baseline (293.994 us; speedup 1.0000x reference)
//
#include <hip/hip_runtime.h>
#include <stdint.h>

#define D_DIM 1024
#define INV_T 14.2857142857142857f
#define BK 64
#define NT (D_DIM / BK)   // 16 K-tiles

typedef __attribute__((ext_vector_type(8))) __bf16 bf16x8;
typedef __attribute__((ext_vector_type(4))) float f32x4;

static __device__ __forceinline__ unsigned short f2bf(float x) {
  union { float f; unsigned int u; } v; v.f = x;
  unsigned int r = v.u + 0x7FFFu + ((v.u >> 16) & 1u);
  return (unsigned short)(r >> 16);
}

// ---------------- Kernel 1: L2-normalize rows (fp32 -> bf16) + diagonal dot ----------------
__global__ __launch_bounds__(256) void norm_diag_kernel(
    const float* __restrict__ A, const float* __restrict__ T,
    unsigned short* __restrict__ An, unsigned short* __restrict__ Tn,
    float* __restrict__ diag)
{
  const int row = blockIdx.x;
  const int tid = threadIdx.x;
  const size_t base = (size_t)row * D_DIM;
  const float4 av = ((const float4*)(A + base))[tid];
  const float4 tv = ((const float4*)(T + base))[tid];
  float sa = av.x*av.x + av.y*av.y + av.z*av.z + av.w*av.w;
  float st = tv.x*tv.x + tv.y*tv.y + tv.z*tv.z + tv.w*tv.w;
  float sd = av.x*tv.x + av.y*tv.y + av.z*tv.z + av.w*tv.w;
  #pragma unroll
  for (int m = 1; m < 64; m <<= 1) {
    sa += __shfl_xor(sa, m, 64);
    st += __shfl_xor(st, m, 64);
    sd += __shfl_xor(sd, m, 64);
  }
  __shared__ float red[3][4];
  const int wid = tid >> 6;
  if ((tid & 63) == 0) { red[0][wid] = sa; red[1][wid] = st; red[2][wid] = sd; }
  __syncthreads();
  sa = red[0][0] + red[0][1] + red[0][2] + red[0][3];
  st = red[1][0] + red[1][1] + red[1][2] + red[1][3];
  sd = red[2][0] + red[2][1] + red[2][2] + red[2][3];
  const float ra = rsqrtf(sa), rt = rsqrtf(st);
  if (tid == 0) diag[row] = sd * ra * rt * INV_T;
  ushort4 ao, to;
  ao.x = f2bf(av.x * ra); ao.y = f2bf(av.y * ra); ao.z = f2bf(av.z * ra); ao.w = f2bf(av.w * ra);
  to.x = f2bf(tv.x * rt); to.y = f2bf(tv.y * rt); to.z = f2bf(tv.z * rt); to.w = f2bf(tv.w * rt);
  ((ushort4*)(An + base))[tid] = ao;
  ((ushort4*)(Tn + base))[tid] = to;
}

// ---------------- Kernel 2: 256x256 8-phase fused GEMM + exp + row/col sum-exp ----------------
__device__ __forceinline__ void gload_lds16(const void* g, void* l) {
  __builtin_amdgcn_global_load_lds(
      (const __attribute__((address_space(1))) unsigned int*)g,
      (__attribute__((address_space(3))) unsigned int*)l, 16, 0, 0);
}

// LDS layout (ushort indices), 128 KB total:
//  buf b (0/1): base b*32768
//    A half h: b*32768 + h*8192           (128 rows x 64 cols bf16, chunk-swizzled)
//    B half h: b*32768 + 16384 + h*8192
#define ASLOT(b,h) ((b)*32768 + (h)*8192)
#define BSLOT(b,h) ((b)*32768 + 16384 + (h)*8192)

// Stage one 128x64 half-tile: 1024 16B-chunks, 2 per thread. LDS dest linear
// (wave-uniform base + lane*16); global source pre-swizzled: LDS chunk (r,c)
// sources global chunk (r, c^(r&7))  [rule #21: both-sides-or-neither].
#define STAGE(PTR, SLOT, TILE, HALF) do {                                       \
    const unsigned short* _sp = (PTR) + (size_t)((HALF)*128) * D_DIM + (TILE)*BK; \
    _Pragma("unroll")                                                           \
    for (int _i = 0; _i < 2; ++_i) {                                            \
      const int _ci = _i*512 + tid;                                             \
      const int _r = _ci >> 3, _c = _ci & 7;                                    \
      gload_lds16(_sp + (size_t)_r * D_DIM + ((_c ^ (_r & 7)) << 3),            \
                  &lds[(SLOT) + _ci*8]);                                        \
    }                                                                           \
  } while (0)

#define SBAR asm volatile("s_barrier" ::: "memory")

// Phase Q (0..3) of one K-tile: block C-quadrant (qa=Q>>1, qb=Q&1), 128x128,
// split 2x4 over waves -> per wave 4 m-frags x 2 n-frags x 2 ksteps = 16 MFMA.
// Reads only A-half qa and B-half qb. Swizzled read: chunk ^= (row&7).
#define PHASE(Q, STAGE_STMT, TAIL_STMT) do {                                    \
    const int _qa = (Q) >> 1, _qb = (Q) & 1;                                    \
    const int _aB = buf*32768 + _qa*8192;                                       \
    const int _bB = buf*32768 + 16384 + _qb*8192;                               \
    bf16x8 _af[4][2], _bf[2][2];                                                \
    _Pragma("unroll")                                                           \
    for (int _mf = 0; _mf < 4; ++_mf) {                                         \
      const int _row = wr*64 + _mf*16 + lcol;                                   \
      _Pragma("unroll")                                                         \
      for (int _ks = 0; _ks < 2; ++_ks) {                                       \
        const int _ch = (_ks*4 + lrow) ^ (_row & 7);                            \
        _af[_mf][_ks] = *(const bf16x8*)&lds[_aB + _row*64 + _ch*8];            \
      }                                                                         \
    }                                                                           \
    _Pragma("unroll")                                                           \
    for (int _nf = 0; _nf < 2; ++_nf) {                                         \
      const int _row = wc*32 + _nf*16 + lcol;                                   \
      _Pragma("unroll")                                                         \
      for (int _ks = 0; _ks < 2; ++_ks) {                                       \
        const int _ch = (_ks*4 + lrow) ^ (_row & 7);                            \
        _bf[_nf][_ks] = *(const bf16x8*)&lds[_bB + _row*64 + _ch*8];            \
      }                                                                         \
    }                                                                           \
    STAGE_STMT;                                                                 \
    SBAR;                                                                       \
    __builtin_amdgcn_s_setprio(1);                                              \
    _Pragma("unroll")                                                           \
    for (int _mf = 0; _mf < 4; ++_mf)                                           \
      _Pragma("unroll")                                                         \
      for (int _nf = 0; _nf < 2; ++_nf)                                         \
        _Pragma("unroll")                                                       \
        for (int _ks = 0; _ks < 2; ++_ks)                                       \
          acc[Q][_mf][_nf] = __builtin_amdgcn_mfma_f32_16x16x32_bf16(           \
              _af[_mf][_ks], _bf[_nf][_ks], acc[Q][_mf][_nf], 0, 0, 0);         \
    __builtin_amdgcn_s_setprio(0);                                              \
    TAIL_STMT;                                                                  \
    SBAR;                                                                       \
  } while (0)

__global__ __launch_bounds__(512, 2) void gemm_lse_kernel(
    const unsigned short* __restrict__ An, const unsigned short* __restrict__ Tn,
    float* __restrict__ Srow, float* __restrict__ Scol, int nbc)
{
  __shared__ unsigned short lds[65536];   // 128 KB

  // XCD-aware bijective swizzle (gridDim.x = 1024, %8 == 0)
  const int nwg = gridDim.x;
  const int bid = blockIdx.x;
  const int cpx = nwg >> 3;
  const int swz = (bid & 7) * cpx + (bid >> 3);
  const int brow = swz / nbc;
  const int bcol = swz - brow * nbc;

  const int tid  = threadIdx.x;
  const int lane = tid & 63;
  const int wid  = tid >> 6;        // 8 waves: 2 (wr) x 4 (wc)
  const int wr   = wid >> 2, wc = wid & 3;
  const int lcol = lane & 15, lrow = lane >> 4;

  const unsigned short* aP = An + (size_t)brow * 256 * D_DIM;
  const unsigned short* bP = Tn + (size_t)bcol * 256 * D_DIM;

  // acc[Q][mf][nf]: quadrant Q=(qa<<1)|qb; per-wave output rows
  //   qa*128 + wr*64 + mf*16 + lrow*4 + reg, cols qb*128 + wc*32 + nf*16 + lcol
  f32x4 acc[4][4][2] = {};

  // Prologue: t0 all 4 halves + t1.Ah0 + t1.Bh0; wait all-of-t0 (2 halves stay in flight)
  STAGE(aP, ASLOT(0,0), 0, 0);
  STAGE(bP, BSLOT(0,0), 0, 0);
  STAGE(bP, BSLOT(0,1), 0, 1);
  STAGE(aP, ASLOT(0,1), 0, 1);
  STAGE(aP, ASLOT(1,0), 1, 0);
  STAGE(bP, BSLOT(1,0), 1, 0);
  asm volatile("s_waitcnt vmcnt(4)" ::: "memory");
  SBAR;

  for (int t = 0; t < NT; ++t) {
    const int buf = t & 1, nb = buf ^ 1;
    const int tn  = (t + 1) & (NT - 1);   // next tile (wraps harmlessly at tail)
    const int tnn = (t + 2) & (NT - 1);   // next-next tile
    // Stage schedule (slot-free proof): q0 -> next.Bh1 (other buf, tile t-1 done)
    //   q1 -> next.Ah1 (other buf); q2 -> nextnext.Ah0 (this buf, A0 last read q1)
    //   q3 -> nextnext.Bh0 (this buf, B0 last read q2)
    // Single vmcnt(4) at q3: leaves {nextnext.Ah0, nextnext.Bh0} in flight,
    // guarantees ALL of tile t+1 (Ah0/Bh0 staged 1 tile ago, Bh1/Ah1 at q0/q1).
    PHASE(0, STAGE(bP, BSLOT(nb,1), tn, 1), (void)0);
    PHASE(1, STAGE(aP, ASLOT(nb,1), tn, 1), (void)0);
    PHASE(2, STAGE(aP, ASLOT(buf,0), tnn, 0), (void)0);
    PHASE(3, STAGE(bP, BSLOT(buf,0), tnn, 0),
             asm volatile("s_waitcnt vmcnt(4)" ::: "memory"));
  }
  asm volatile("s_waitcnt vmcnt(0)" ::: "memory");  // drain tail stages before endpgm

  // ---- Epilogue: e = exp(sim * INV_T); row/col partial sums -> atomics ----
  float rowp[2][4][4];   // [qa][mf][reg] : sum over qb,nf,lcol-lanes
  float colp[2][2];      // [qb][nf]      : sum over qa,mf,reg,lrow-lanes
  #pragma unroll
  for (int qa = 0; qa < 2; ++qa)
    #pragma unroll
    for (int mf = 0; mf < 4; ++mf)
      #pragma unroll
      for (int r = 0; r < 4; ++r) rowp[qa][mf][r] = 0.f;
  #pragma unroll
  for (int qb = 0; qb < 2; ++qb) { colp[qb][0] = 0.f; colp[qb][1] = 0.f; }

  #pragma unroll
  for (int q = 0; q < 4; ++q) {
    const int qa = q >> 1, qb = q & 1;
    #pragma unroll
    for (int mf = 0; mf < 4; ++mf)
      #pragma unroll
      for (int nf = 0; nf < 2; ++nf)
        #pragma unroll
        for (int r = 0; r < 4; ++r) {
          const float e = __expf(acc[q][mf][nf][r] * INV_T);
          rowp[qa][mf][r] += e;
          colp[qb][nf] += e;
        }
  }
  // Row sums: reduce over the 16 lanes (lane bits 0-3) of each row
  #pragma unroll
  for (int qa = 0; qa < 2; ++qa)
    #pragma unroll
    for (int mf = 0; mf < 4; ++mf)
      #pragma unroll
      for (int r = 0; r < 4; ++r) {
        float v = rowp[qa][mf][r];
        v += __shfl_xor(v, 1, 64);
        v += __shfl_xor(v, 2, 64);
        v += __shfl_xor(v, 4, 64);
        v += __shfl_xor(v, 8, 64);
        if (lcol == 0)
          atomicAdd(&Srow[brow*256 + qa*128 + wr*64 + mf*16 + lrow*4 + r], v);
      }
  // Col sums: reduce over lane bits 4-5 (the 4 row-groups)
  #pragma unroll
  for (int qb = 0; qb < 2; ++qb)
    #pragma unroll
    for (int nf = 0; nf < 2; ++nf) {
      float v = colp[qb][nf];
      v += __shfl_xor(v, 16, 64);
      v += __shfl_xor(v, 32, 64);
      if (lrow == 0)
        atomicAdd(&Scol[bcol*256 + qb*128 + wc*32 + nf*16 + lcol], v);
    }
}

// ---------------- Kernel 3: loss = mean(0.5*(log Srow + log Scol) - diag) ----------------
__global__ __launch_bounds__(256) void loss_kernel(
    const float* __restrict__ Srow, const float* __restrict__ Scol,
    const float* __restrict__ diag, float* __restrict__ out, int B)
{
  float s = 0.f;
  for (int i = threadIdx.x; i < B; i += 256)
    s += 0.5f * (__logf(Srow[i]) + __logf(Scol[i])) - diag[i];
  #pragma unroll
  for (int m = 1; m < 64; m <<= 1) s += __shfl_xor(s, m, 64);
  __shared__ float red[4];
  if ((threadIdx.x & 63) == 0) red[threadIdx.x >> 6] = s;
  __syncthreads();
  if (threadIdx.x == 0) out[0] = (red[0] + red[1] + red[2] + red[3]) / (float)B;
}

extern "C" void kernel_launch(void* const* d_in, const int* in_sizes, int n_in,
                              void* d_out, int out_size, void* d_ws, size_t ws_size,
                              hipStream_t stream) {
  const float* A = (const float*)d_in[0];
  const float* T = (const float*)d_in[1];
  const int B = in_sizes[0] / D_DIM;     // 8192
  const int nbc = B / 256;               // 32

  char* ws = (char*)d_ws;
  unsigned short* An = (unsigned short*)ws;                           // 16 MB
  unsigned short* Tn = (unsigned short*)(ws + (size_t)B * D_DIM * 2); // 16 MB
  float* Srow = (float*)(ws + (size_t)B * D_DIM * 4);
  float* Scol = Srow + B;
  float* diag = Scol + B;

  hipMemsetAsync(Srow, 0, (size_t)2 * B * sizeof(float), stream);
  norm_diag_kernel<<<B, 256, 0, stream>>>(A, T, An, Tn, diag);
  gemm_lse_kernel<<<nbc * nbc, 512, 0, stream>>>(An, Tn, Srow, Scol, nbc);
  loss_kernel<<<1, 256, 0, stream>>>(Srow, Scol, diag, (float*)d_out, B);
}

// Round 3
// 252.995 us; speedup vs baseline: 1.1621x; 1.1621x over previous
//
#include <hip/hip_runtime.h>
#include <stdint.h>

#define D_DIM 1024
#define INV_T 14.2857142857142857f
#define BK 64
#define NT (D_DIM / BK)   // 16 K-tiles

typedef __attribute__((ext_vector_type(8))) __bf16 bf16x8;
typedef __attribute__((ext_vector_type(4))) float f32x4;

static __device__ __forceinline__ unsigned short f2bf(float x) {
  union { float f; unsigned int u; } v; v.f = x;
  unsigned int r = v.u + 0x7FFFu + ((v.u >> 16) & 1u);
  return (unsigned short)(r >> 16);
}

// ---------------- Kernel 1: L2-normalize rows (fp32 -> bf16) + diagonal dot ----------------
__global__ __launch_bounds__(256) void norm_diag_kernel(
    const float* __restrict__ A, const float* __restrict__ T,
    unsigned short* __restrict__ An, unsigned short* __restrict__ Tn,
    float* __restrict__ diag)
{
  const int row = blockIdx.x;
  const int tid = threadIdx.x;
  const size_t base = (size_t)row * D_DIM;
  const float4 av = ((const float4*)(A + base))[tid];
  const float4 tv = ((const float4*)(T + base))[tid];
  float sa = av.x*av.x + av.y*av.y + av.z*av.z + av.w*av.w;
  float st = tv.x*tv.x + tv.y*tv.y + tv.z*tv.z + tv.w*tv.w;
  float sd = av.x*tv.x + av.y*tv.y + av.z*tv.z + av.w*tv.w;
  #pragma unroll
  for (int m = 1; m < 64; m <<= 1) {
    sa += __shfl_xor(sa, m, 64);
    st += __shfl_xor(st, m, 64);
    sd += __shfl_xor(sd, m, 64);
  }
  __shared__ float red[3][4];
  const int wid = tid >> 6;
  if ((tid & 63) == 0) { red[0][wid] = sa; red[1][wid] = st; red[2][wid] = sd; }
  __syncthreads();
  sa = red[0][0] + red[0][1] + red[0][2] + red[0][3];
  st = red[1][0] + red[1][1] + red[1][2] + red[1][3];
  sd = red[2][0] + red[2][1] + red[2][2] + red[2][3];
  const float ra = rsqrtf(sa), rt = rsqrtf(st);
  if (tid == 0) diag[row] = sd * ra * rt * INV_T;
  ushort4 ao, to;
  ao.x = f2bf(av.x * ra); ao.y = f2bf(av.y * ra); ao.z = f2bf(av.z * ra); ao.w = f2bf(av.w * ra);
  to.x = f2bf(tv.x * rt); to.y = f2bf(tv.y * rt); to.z = f2bf(tv.z * rt); to.w = f2bf(tv.w * rt);
  ((ushort4*)(An + base))[tid] = ao;
  ((ushort4*)(Tn + base))[tid] = to;
}

// ---------------- Kernel 2: 256x256 8-phase fused GEMM + exp + row/col sum-exp ----------------
__device__ __forceinline__ void gload_lds16(const void* g, void* l) {
  __builtin_amdgcn_global_load_lds(
      (const __attribute__((address_space(1))) unsigned int*)g,
      (__attribute__((address_space(3))) unsigned int*)l, 16, 0, 0);
}

// LDS layout (ushort indices), 128 KB total:
//  buf b (0/1): base b*32768
//    A half h: b*32768 + h*8192           (128 rows x 64 cols bf16, chunk-swizzled)
//    B half h: b*32768 + 16384 + h*8192
#define ASLOT(b,h) ((b)*32768 + (h)*8192)
#define BSLOT(b,h) ((b)*32768 + 16384 + (h)*8192)

// Stage one 128x64 half-tile: 1024 16B-chunks, 2 per thread. LDS dest linear
// (wave-uniform base + lane*16); global source pre-swizzled: LDS chunk (r,c)
// sources global chunk (r, c^(r&7))  [rule #21: both-sides-or-neither].
#define STAGE(PTR, SLOT, TILE, HALF) do {                                       \
    const unsigned short* _sp = (PTR) + (size_t)((HALF)*128) * D_DIM + (TILE)*BK; \
    _Pragma("unroll")                                                           \
    for (int _i = 0; _i < 2; ++_i) {                                            \
      const int _ci = _i*512 + tid;                                             \
      const int _r = _ci >> 3, _c = _ci & 7;                                    \
      gload_lds16(_sp + (size_t)_r * D_DIM + ((_c ^ (_r & 7)) << 3),            \
                  &lds[(SLOT) + _ci*8]);                                        \
    }                                                                           \
  } while (0)

#define SBAR asm volatile("s_barrier" ::: "memory")

// Fragment loads (swizzled read: chunk ^= row&7)
#define RD_A(dst, QA) do {                                                      \
    const int _aB = buf*32768 + (QA)*8192;                                      \
    _Pragma("unroll")                                                           \
    for (int _mf = 0; _mf < 4; ++_mf) {                                         \
      const int _row = wr*64 + _mf*16 + lcol;                                   \
      _Pragma("unroll")                                                         \
      for (int _ks = 0; _ks < 2; ++_ks) {                                       \
        const int _ch = (_ks*4 + lrow) ^ (_row & 7);                            \
        dst[_mf][_ks] = *(const bf16x8*)&lds[_aB + _row*64 + _ch*8];            \
      }                                                                         \
    }                                                                           \
  } while (0)

#define RD_B(dst, QB) do {                                                      \
    const int _bB = buf*32768 + 16384 + (QB)*8192;                              \
    _Pragma("unroll")                                                           \
    for (int _nf = 0; _nf < 2; ++_nf) {                                         \
      const int _row = wc*32 + _nf*16 + lcol;                                   \
      _Pragma("unroll")                                                         \
      for (int _ks = 0; _ks < 2; ++_ks) {                                       \
        const int _ch = (_ks*4 + lrow) ^ (_row & 7);                            \
        dst[_nf][_ks] = *(const bf16x8*)&lds[_bB + _row*64 + _ch*8];            \
      }                                                                         \
    }                                                                           \
  } while (0)

#define MFMA_Q(Q, AF, BF) do {                                                  \
    __builtin_amdgcn_s_setprio(1);                                              \
    _Pragma("unroll")                                                           \
    for (int _mf = 0; _mf < 4; ++_mf)                                           \
      _Pragma("unroll")                                                         \
      for (int _nf = 0; _nf < 2; ++_nf)                                         \
        _Pragma("unroll")                                                       \
        for (int _ks = 0; _ks < 2; ++_ks)                                       \
          acc[Q][_mf][_nf] = __builtin_amdgcn_mfma_f32_16x16x32_bf16(           \
              AF[_mf][_ks], BF[_nf][_ks], acc[Q][_mf][_nf], 0, 0, 0);           \
    __builtin_amdgcn_s_setprio(0);                                              \
  } while (0)

__global__ __launch_bounds__(512, 2) void gemm_lse_kernel(
    const unsigned short* __restrict__ An, const unsigned short* __restrict__ Tn,
    float* __restrict__ Srow, float* __restrict__ Scol, int nbc)
{
  __shared__ unsigned short lds[65536];   // 128 KB

  // XCD-aware bijective swizzle (gridDim.x = 1024, %8 == 0)
  const int nwg = gridDim.x;
  const int bid = blockIdx.x;
  const int cpx = nwg >> 3;
  const int swz = (bid & 7) * cpx + (bid >> 3);
  const int brow = swz / nbc;
  const int bcol = swz - brow * nbc;

  const int tid  = threadIdx.x;
  const int lane = tid & 63;
  const int wid  = tid >> 6;        // 8 waves: 2 (wr) x 4 (wc)
  const int wr   = wid >> 2, wc = wid & 3;
  const int lcol = lane & 15, lrow = lane >> 4;

  const unsigned short* aP = An + (size_t)brow * 256 * D_DIM;
  const unsigned short* bP = Tn + (size_t)bcol * 256 * D_DIM;

  // acc[Q][mf][nf]: quadrant Q=(qa<<1)|qb; per-wave output rows
  //   qa*128 + wr*64 + mf*16 + lrow*4 + reg, cols qb*128 + wc*32 + nf*16 + lcol
  f32x4 acc[4][4][2] = {};

  // Prologue: tile0 all 4 halves into buf0; tile1's {Ah0, Bh1} (the 2-ahead
  // slots) into buf1. vmcnt(4): tile0 resident, tile1 pair stays in flight.
  STAGE(aP, ASLOT(0,0), 0, 0);
  STAGE(bP, BSLOT(0,0), 0, 0);
  STAGE(bP, BSLOT(0,1), 0, 1);
  STAGE(aP, ASLOT(0,1), 0, 1);
  STAGE(aP, ASLOT(1,0), 1, 0);
  STAGE(bP, BSLOT(1,1), 1, 1);
  asm volatile("s_waitcnt vmcnt(4)" ::: "memory");
  SBAR;

  // Phase snake order (qa,qb): (0,0)->(0,1)->(1,1)->(1,0); fragments reused
  // across consecutive phases -> 28 ds_read_b128/wave/K-tile (vs 48 naive).
  // Stage schedule: P0 -> nb.Ah1 (tile t+1), P1 -> nb.Bh0 (tile t+1),
  //   P2 -> buf.Ah0 (tile t+2; Ah0 last LDS-read at P0, barrier-closed),
  //   P3 -> buf.Bh1 (tile t+2; Bh1 last LDS-read at P2, barrier-closed).
  // vmcnt(4) once per tile at P3: drains prev-iter's P2/P3 + this iter's
  // P0/P1 -> ALL of tile t+1 resident; leaves this iter's P2/P3 (4 loads,
  // tile t+2 pair) in flight. Never vmcnt(0) in the loop.
  for (int t = 0; t < NT; ++t) {
    const int buf = t & 1, nb = buf ^ 1;
    const int tn  = (t + 1) & (NT - 1);
    const int tnn = (t + 2) & (NT - 1);
    bf16x8 af[4][2], b0[2][2], b1[2][2];

    // P0: Q00 — read A0 + B0
    RD_A(af, 0); RD_B(b0, 0);
    STAGE(aP, ASLOT(nb,1), tn, 1);
    SBAR;
    MFMA_Q(0, af, b0);
    SBAR;
    // P1: Q01 — reuse A0, read B1
    RD_B(b1, 1);
    STAGE(bP, BSLOT(nb,0), tn, 0);
    SBAR;
    MFMA_Q(1, af, b1);
    SBAR;
    // P2: Q11 — read A1, reuse B1
    RD_A(af, 1);
    STAGE(aP, ASLOT(buf,0), tnn, 0);
    SBAR;
    MFMA_Q(3, af, b1);
    SBAR;
    // P3: Q10 — reuse A1, re-read B0
    RD_B(b0, 0);
    STAGE(bP, BSLOT(buf,1), tnn, 1);
    asm volatile("s_waitcnt vmcnt(4)" ::: "memory");
    SBAR;
    MFMA_Q(2, af, b0);
    SBAR;
  }
  asm volatile("s_waitcnt vmcnt(0)" ::: "memory");  // drain tail stages

  // ---- Epilogue: e = exp(sim * INV_T); row/col partial sums -> atomics ----
  float rowp[2][4][4];   // [qa][mf][reg]
  float colp[2][2];      // [qb][nf]
  #pragma unroll
  for (int qa = 0; qa < 2; ++qa)
    #pragma unroll
    for (int mf = 0; mf < 4; ++mf)
      #pragma unroll
      for (int r = 0; r < 4; ++r) rowp[qa][mf][r] = 0.f;
  #pragma unroll
  for (int qb = 0; qb < 2; ++qb) { colp[qb][0] = 0.f; colp[qb][1] = 0.f; }

  #pragma unroll
  for (int q = 0; q < 4; ++q) {
    const int qa = q >> 1, qb = q & 1;
    #pragma unroll
    for (int mf = 0; mf < 4; ++mf)
      #pragma unroll
      for (int nf = 0; nf < 2; ++nf)
        #pragma unroll
        for (int r = 0; r < 4; ++r) {
          const float e = __expf(acc[q][mf][nf][r] * INV_T);
          rowp[qa][mf][r] += e;
          colp[qb][nf] += e;
        }
  }
  #pragma unroll
  for (int qa = 0; qa < 2; ++qa)
    #pragma unroll
    for (int mf = 0; mf < 4; ++mf)
      #pragma unroll
      for (int r = 0; r < 4; ++r) {
        float v = rowp[qa][mf][r];
        v += __shfl_xor(v, 1, 64);
        v += __shfl_xor(v, 2, 64);
        v += __shfl_xor(v, 4, 64);
        v += __shfl_xor(v, 8, 64);
        if (lcol == 0)
          atomicAdd(&Srow[brow*256 + qa*128 + wr*64 + mf*16 + lrow*4 + r], v);
      }
  #pragma unroll
  for (int qb = 0; qb < 2; ++qb)
    #pragma unroll
    for (int nf = 0; nf < 2; ++nf) {
      float v = colp[qb][nf];
      v += __shfl_xor(v, 16, 64);
      v += __shfl_xor(v, 32, 64);
      if (lrow == 0)
        atomicAdd(&Scol[bcol*256 + qb*128 + wc*32 + nf*16 + lcol], v);
    }
}

// ---------------- Kernel 3: loss = mean(0.5*(log Srow + log Scol) - diag) ----------------
__global__ __launch_bounds__(256) void loss_kernel(
    const float* __restrict__ Srow, const float* __restrict__ Scol,
    const float* __restrict__ diag, float* __restrict__ out, int B)
{
  float s = 0.f;
  for (int i = threadIdx.x; i < B; i += 256)
    s += 0.5f * (__logf(Srow[i]) + __logf(Scol[i])) - diag[i];
  #pragma unroll
  for (int m = 1; m < 64; m <<= 1) s += __shfl_xor(s, m, 64);
  __shared__ float red[4];
  if ((threadIdx.x & 63) == 0) red[threadIdx.x >> 6] = s;
  __syncthreads();
  if (threadIdx.x == 0) out[0] = (red[0] + red[1] + red[2] + red[3]) / (float)B;
}

extern "C" void kernel_launch(void* const* d_in, const int* in_sizes, int n_in,
                              void* d_out, int out_size, void* d_ws, size_t ws_size,
                              hipStream_t stream) {
  const float* A = (const float*)d_in[0];
  const float* T = (const float*)d_in[1];
  const int B = in_sizes[0] / D_DIM;     // 8192
  const int nbc = B / 256;               // 32

  char* ws = (char*)d_ws;
  unsigned short* An = (unsigned short*)ws;                           // 16 MB
  unsigned short* Tn = (unsigned short*)(ws + (size_t)B * D_DIM * 2); // 16 MB
  float* Srow = (float*)(ws + (size_t)B * D_DIM * 4);
  float* Scol = Srow + B;
  float* diag = Scol + B;

  hipMemsetAsync(Srow, 0, (size_t)2 * B * sizeof(float), stream);
  norm_diag_kernel<<<B, 256, 0, stream>>>(A, T, An, Tn, diag);
  gemm_lse_kernel<<<nbc * nbc, 512, 0, stream>>>(An, Tn, Srow, Scol, nbc);
  loss_kernel<<<1, 256, 0, stream>>>(Srow, Scol, diag, (float*)d_out, B);
}

// Round 4
// 239.619 us; speedup vs baseline: 1.2269x; 1.0558x over previous
//
#include <hip/hip_runtime.h>
#include <stdint.h>

#define D_DIM 1024
#define INV_T 14.2857142857142857f
#define BK 64
#define NT (D_DIM / BK)   // 16 K-tiles

typedef __attribute__((ext_vector_type(8))) __bf16 bf16x8;
typedef __attribute__((ext_vector_type(4))) float f32x4;

static __device__ __forceinline__ unsigned short f2bf(float x) {
  union { float f; unsigned int u; } v; v.f = x;
  unsigned int r = v.u + 0x7FFFu + ((v.u >> 16) & 1u);
  return (unsigned short)(r >> 16);
}

// ---------------- Kernel 1: L2-normalize rows (fp32 -> bf16) + diagonal dot ----------------
__global__ __launch_bounds__(256) void norm_diag_kernel(
    const float* __restrict__ A, const float* __restrict__ T,
    unsigned short* __restrict__ An, unsigned short* __restrict__ Tn,
    float* __restrict__ diag)
{
  const int row = blockIdx.x;
  const int tid = threadIdx.x;
  const size_t base = (size_t)row * D_DIM;
  const float4 av = ((const float4*)(A + base))[tid];
  const float4 tv = ((const float4*)(T + base))[tid];
  float sa = av.x*av.x + av.y*av.y + av.z*av.z + av.w*av.w;
  float st = tv.x*tv.x + tv.y*tv.y + tv.z*tv.z + tv.w*tv.w;
  float sd = av.x*tv.x + av.y*tv.y + av.z*tv.z + av.w*tv.w;
  #pragma unroll
  for (int m = 1; m < 64; m <<= 1) {
    sa += __shfl_xor(sa, m, 64);
    st += __shfl_xor(st, m, 64);
    sd += __shfl_xor(sd, m, 64);
  }
  __shared__ float red[3][4];
  const int wid = tid >> 6;
  if ((tid & 63) == 0) { red[0][wid] = sa; red[1][wid] = st; red[2][wid] = sd; }
  __syncthreads();
  sa = red[0][0] + red[0][1] + red[0][2] + red[0][3];
  st = red[1][0] + red[1][1] + red[1][2] + red[1][3];
  sd = red[2][0] + red[2][1] + red[2][2] + red[2][3];
  const float ra = rsqrtf(sa), rt = rsqrtf(st);
  if (tid == 0) diag[row] = sd * ra * rt * INV_T;
  ushort4 ao, to;
  ao.x = f2bf(av.x * ra); ao.y = f2bf(av.y * ra); ao.z = f2bf(av.z * ra); ao.w = f2bf(av.w * ra);
  to.x = f2bf(tv.x * rt); to.y = f2bf(tv.y * rt); to.z = f2bf(tv.z * rt); to.w = f2bf(tv.w * rt);
  ((ushort4*)(An + base))[tid] = ao;
  ((ushort4*)(Tn + base))[tid] = to;
}

// ---------------- Kernel 2: 128x128 double-buffered fused GEMM + exp + row/col sum-exp ----------------
__device__ __forceinline__ void gload_lds16(const void* g, void* l) {
  __builtin_amdgcn_global_load_lds(
      (const __attribute__((address_space(1))) unsigned int*)g,
      (__attribute__((address_space(3))) unsigned int*)l, 16, 0, 0);
}

#define SBAR asm volatile("s_barrier" ::: "memory")

// Stage tile T (both operands) into buf (T&1). 1024 16B-chunks per operand,
// 4 per thread per operand (8 vmcnt ops per thread total).
// LDS dest linear (HW: wave-uniform base + lane*16); swizzle applied on the
// GLOBAL source: LDS chunk (r,c) holds global chunk (r, c^(r&7)) [rule #21].
#define STAGE2(T) do {                                                          \
    const unsigned short* _a = aP + (size_t)(T) * BK;                           \
    const unsigned short* _b = bP + (size_t)(T) * BK;                           \
    const int _bb = ((T) & 1) * 16384;                                          \
    _Pragma("unroll")                                                           \
    for (int _i = 0; _i < 4; ++_i) {                                            \
      const int _ci = _i*256 + tid;                                             \
      const int _r = _ci >> 3, _c = _ci & 7;                                    \
      const size_t _go = (size_t)_r * D_DIM + ((_c ^ (_r & 7)) << 3);           \
      gload_lds16(_a + _go, &lds[_bb + _ci*8]);                                 \
      gload_lds16(_b + _go, &lds[_bb + 8192 + _ci*8]);                          \
    }                                                                           \
  } while (0)

__global__ __launch_bounds__(256, 2) void gemm_lse_kernel(
    const unsigned short* __restrict__ An, const unsigned short* __restrict__ Tn,
    float* __restrict__ Srow, float* __restrict__ Scol, int nbc)
{
  // [buf(2)][op(2)][128 rows][8 chunks of 8 ushort] = 64 KB -> 2 blocks/CU
  __shared__ unsigned short lds[32768];

  // XCD-aware bijective swizzle (gridDim.x = 4096, %8 == 0)
  const int nwg = gridDim.x;
  const int bid = blockIdx.x;
  const int cpx = nwg >> 3;
  const int swz = (bid & 7) * cpx + (bid >> 3);
  const int brow = swz / nbc;
  const int bcol = swz - brow * nbc;

  const int tid  = threadIdx.x;
  const int lane = tid & 63;
  const int wid  = tid >> 6;        // 4 waves, 2x2; each wave owns 64x64 output
  const int wr   = wid >> 1, wc = wid & 1;
  const int lcol = lane & 15, lrow = lane >> 4;

  const unsigned short* aP = An + (size_t)brow * 128 * D_DIM;
  const unsigned short* bP = Tn + (size_t)bcol * 128 * D_DIM;

  f32x4 acc[4][4] = {};

  // Prologue: stage tile0 -> buf0, tile1 -> buf1 (16 loads/thread);
  // vmcnt(8) waits tile0's 8 (in-order retirement), keeps tile1's 8 in flight.
  STAGE2(0);
  STAGE2(1);
  asm volatile("s_waitcnt vmcnt(8)" ::: "memory");
  SBAR;

  for (int t = 0; t < NT; ++t) {
    const int bb = (t & 1) * 16384;
    #pragma unroll
    for (int kk = 0; kk < 64; kk += 32) {
      // logical chunk = kk/8 + lrow; swizzled slot = chunk ^ (row&7)
      bf16x8 af[4], bfr[4];
      #pragma unroll
      for (int m = 0; m < 4; ++m) {
        const int row = wr*64 + m*16 + lcol;
        const int sl = ((kk >> 3) + lrow) ^ (row & 7);
        af[m] = *(const bf16x8*)&lds[bb + row*64 + sl*8];
      }
      #pragma unroll
      for (int n = 0; n < 4; ++n) {
        const int row = wc*64 + n*16 + lcol;
        const int sl = ((kk >> 3) + lrow) ^ (row & 7);
        bfr[n] = *(const bf16x8*)&lds[bb + 8192 + row*64 + sl*8];
      }
      #pragma unroll
      for (int m = 0; m < 4; ++m)
        #pragma unroll
        for (int n = 0; n < 4; ++n)
          acc[m][n] = __builtin_amdgcn_mfma_f32_16x16x32_bf16(af[m], bfr[n], acc[m][n], 0, 0, 0);
    }
    // Seal all waves' reads of this buf, then refill it with tile t+2.
    SBAR;
    if (t + 2 < NT) {
      STAGE2(t + 2);
      // Outstanding: t+1's 8 + t+2's 8. Wait t+1 resident; keep t+2 in flight.
      asm volatile("s_waitcnt vmcnt(8)" ::: "memory");
    } else {
      // t==NT-2: drain t+1's loads (issued 1 tile ago). t==NT-1: no-op.
      asm volatile("s_waitcnt vmcnt(0)" ::: "memory");
    }
    SBAR;
  }

  // ---- Epilogue: e = exp(sim * INV_T); row/col partial sums -> atomics ----
  // C/D mapping: col = lane&15, row = (lane>>4)*4 + reg
  float rowsum[4][4];
  float colsum[4];
  #pragma unroll
  for (int m = 0; m < 4; ++m)
    #pragma unroll
    for (int r = 0; r < 4; ++r) rowsum[m][r] = 0.f;
  #pragma unroll
  for (int n = 0; n < 4; ++n) {
    float cs = 0.f;
    #pragma unroll
    for (int m = 0; m < 4; ++m)
      #pragma unroll
      for (int r = 0; r < 4; ++r) {
        const float e = __expf(acc[m][n][r] * INV_T);
        rowsum[m][r] += e;
        cs += e;
      }
    colsum[n] = cs;
  }
  #pragma unroll
  for (int m = 0; m < 4; ++m)
    #pragma unroll
    for (int r = 0; r < 4; ++r) {
      float v = rowsum[m][r];
      v += __shfl_xor(v, 1, 64);
      v += __shfl_xor(v, 2, 64);
      v += __shfl_xor(v, 4, 64);
      v += __shfl_xor(v, 8, 64);
      if (lcol == 0)
        atomicAdd(&Srow[brow*128 + wr*64 + m*16 + lrow*4 + r], v);
    }
  #pragma unroll
  for (int n = 0; n < 4; ++n) {
    float v = colsum[n];
    v += __shfl_xor(v, 16, 64);
    v += __shfl_xor(v, 32, 64);
    if (lane < 16)
      atomicAdd(&Scol[bcol*128 + wc*64 + n*16 + lcol], v);
  }
}

// ---------------- Kernel 3: loss = mean(0.5*(log Srow + log Scol) - diag) ----------------
__global__ __launch_bounds__(256) void loss_kernel(
    const float* __restrict__ Srow, const float* __restrict__ Scol,
    const float* __restrict__ diag, float* __restrict__ out, int B)
{
  float s = 0.f;
  for (int i = threadIdx.x; i < B; i += 256)
    s += 0.5f * (__logf(Srow[i]) + __logf(Scol[i])) - diag[i];
  #pragma unroll
  for (int m = 1; m < 64; m <<= 1) s += __shfl_xor(s, m, 64);
  __shared__ float red[4];
  if ((threadIdx.x & 63) == 0) red[threadIdx.x >> 6] = s;
  __syncthreads();
  if (threadIdx.x == 0) out[0] = (red[0] + red[1] + red[2] + red[3]) / (float)B;
}

extern "C" void kernel_launch(void* const* d_in, const int* in_sizes, int n_in,
                              void* d_out, int out_size, void* d_ws, size_t ws_size,
                              hipStream_t stream) {
  const float* A = (const float*)d_in[0];
  const float* T = (const float*)d_in[1];
  const int B = in_sizes[0] / D_DIM;     // 8192
  const int nbc = B / 128;               // 64

  char* ws = (char*)d_ws;
  unsigned short* An = (unsigned short*)ws;                           // 16 MB
  unsigned short* Tn = (unsigned short*)(ws + (size_t)B * D_DIM * 2); // 16 MB
  float* Srow = (float*)(ws + (size_t)B * D_DIM * 4);
  float* Scol = Srow + B;
  float* diag = Scol + B;

  hipMemsetAsync(Srow, 0, (size_t)2 * B * sizeof(float), stream);
  norm_diag_kernel<<<B, 256, 0, stream>>>(A, T, An, Tn, diag);
  gemm_lse_kernel<<<nbc * nbc, 256, 0, stream>>>(An, Tn, Srow, Scol, nbc);
  loss_kernel<<<1, 256, 0, stream>>>(Srow, Scol, diag, (float*)d_out, B);
}

// Round 5
// 169.679 us; speedup vs baseline: 1.7326x; 1.4122x over previous
//
#include <hip/hip_runtime.h>
#include <stdint.h>

#define D_DIM 1024
#define INV_T 14.2857142857142857f
#define QSCALE 32.0f
#define EPI_SCALE (INV_T / (QSCALE * QSCALE))   // dequant (32a)(32b) + /T
#define BK 64
#define NT (D_DIM / BK)   // 16 K-tiles

typedef __attribute__((ext_vector_type(4))) float f32x4;

// ---------------- Kernel 1: L2-normalize rows (fp32 -> fp8 e4m3 x32) + diagonal dot ----------------
__global__ __launch_bounds__(256) void norm_diag_kernel(
    const float* __restrict__ A, const float* __restrict__ T,
    unsigned int* __restrict__ An, unsigned int* __restrict__ Tn,
    float* __restrict__ diag)
{
  const int row = blockIdx.x;
  const int tid = threadIdx.x;              // 256 threads x 4 elems (D=1024)
  const size_t base = (size_t)row * D_DIM;
  const float4 av = ((const float4*)(A + base))[tid];
  const float4 tv = ((const float4*)(T + base))[tid];
  float sa = av.x*av.x + av.y*av.y + av.z*av.z + av.w*av.w;
  float st = tv.x*tv.x + tv.y*tv.y + tv.z*tv.z + tv.w*tv.w;
  float sd = av.x*tv.x + av.y*tv.y + av.z*tv.z + av.w*tv.w;
  #pragma unroll
  for (int m = 1; m < 64; m <<= 1) {
    sa += __shfl_xor(sa, m, 64);
    st += __shfl_xor(st, m, 64);
    sd += __shfl_xor(sd, m, 64);
  }
  __shared__ float red[3][4];
  const int wid = tid >> 6;
  if ((tid & 63) == 0) { red[0][wid] = sa; red[1][wid] = st; red[2][wid] = sd; }
  __syncthreads();
  sa = red[0][0] + red[0][1] + red[0][2] + red[0][3];
  st = red[1][0] + red[1][1] + red[1][2] + red[1][3];
  sd = red[2][0] + red[2][1] + red[2][2] + red[2][3];
  const float ra = rsqrtf(sa), rt = rsqrtf(st);
  if (tid == 0) diag[row] = sd * ra * rt * INV_T;   // diag term in exact fp32
  const float qa = ra * QSCALE, qt = rt * QSCALE;
  // pack 4 floats -> 4 fp8 bytes (OCP e4m3 on gfx950), byte i = elem i
  unsigned int ao = __builtin_amdgcn_cvt_pk_fp8_f32(av.x*qa, av.y*qa, 0, 0);
  ao = __builtin_amdgcn_cvt_pk_fp8_f32(av.z*qa, av.w*qa, ao, 1);
  unsigned int to = __builtin_amdgcn_cvt_pk_fp8_f32(tv.x*qt, tv.y*qt, 0, 0);
  to = __builtin_amdgcn_cvt_pk_fp8_f32(tv.z*qt, tv.w*qt, to, 1);
  An[row * 256 + tid] = ao;
  Tn[row * 256 + tid] = to;
}

// ---------------- Kernel 2: 128x128 fp8 double-buffered fused GEMM + exp + row/col sum-exp ----------------
__device__ __forceinline__ void gload_lds16(const void* g, void* l) {
  __builtin_amdgcn_global_load_lds(
      (const __attribute__((address_space(1))) unsigned int*)g,
      (__attribute__((address_space(3))) unsigned int*)l, 16, 0, 0);
}

#define SBAR asm volatile("s_barrier" ::: "memory")

// Stage tile T (both operands) into buf (T&1). Per operand: 128 rows x 64 B
// = 512 16B-chunks, 2 per thread (4 vmcnt ops/thread total).
// LDS dest linear (HW: wave-uniform base + lane*16); swizzle on the GLOBAL
// source: LDS chunk (r,c) holds global chunk (r, c ^ ((r>>1)&3)) — i.e. 8B
// slot s' = s ^ (r&6), which keeps 16B chunks intact [rule #21].
#define STAGE2(T) do {                                                          \
    const unsigned char* _a = aP + (size_t)(T) * BK;                            \
    const unsigned char* _b = bP + (size_t)(T) * BK;                            \
    const int _bb = ((T) & 1) * 16384;                                          \
    _Pragma("unroll")                                                           \
    for (int _i = 0; _i < 2; ++_i) {                                            \
      const int _ci = _i*256 + tid;                                             \
      const int _r = _ci >> 2, _c = _ci & 3;                                    \
      const size_t _go = (size_t)_r * D_DIM + ((_c ^ ((_r >> 1) & 3)) << 4);    \
      gload_lds16(_a + _go, &lds[_bb + _ci*16]);                                \
      gload_lds16(_b + _go, &lds[_bb + 8192 + _ci*16]);                         \
    }                                                                           \
  } while (0)

__global__ __launch_bounds__(256, 4) void gemm_lse_kernel(
    const unsigned char* __restrict__ An, const unsigned char* __restrict__ Tn,
    float* __restrict__ Srow, float* __restrict__ Scol, int nbc)
{
  // [buf(2)][op(2)][128 rows][64 B] = 32 KB -> 4-5 blocks/CU
  __shared__ unsigned char lds[32768];

  // XCD-aware bijective swizzle (gridDim.x = 4096, %8 == 0)
  const int nwg = gridDim.x;
  const int bid = blockIdx.x;
  const int cpx = nwg >> 3;
  const int swz = (bid & 7) * cpx + (bid >> 3);
  const int brow = swz / nbc;
  const int bcol = swz - brow * nbc;

  const int tid  = threadIdx.x;
  const int lane = tid & 63;
  const int wid  = tid >> 6;        // 4 waves, 2x2; each wave owns 64x64 output
  const int wr   = wid >> 1, wc = wid & 1;
  const int lcol = lane & 15, lrow = lane >> 4;

  const unsigned char* aP = An + (size_t)brow * 128 * D_DIM;
  const unsigned char* bP = Tn + (size_t)bcol * 128 * D_DIM;

  f32x4 acc[4][4] = {};

  // Prologue: tile0 -> buf0, tile1 -> buf1 (8 loads/thread);
  // vmcnt(4) waits tile0's 4 (in-order retirement), keeps tile1's 4 in flight.
  STAGE2(0);
  STAGE2(1);
  asm volatile("s_waitcnt vmcnt(4)" ::: "memory");
  SBAR;

  for (int t = 0; t < NT; ++t) {
    const int bb = (t & 1) * 16384;
    #pragma unroll
    for (int kk = 0; kk < 2; ++kk) {        // two K=32 steps
      // lane's 8 fp8 at k = kk*32 + lrow*8 -> 8B slot s = kk*4+lrow, swz s^(row&6)
      long af[4], bfr[4];
      #pragma unroll
      for (int m = 0; m < 4; ++m) {
        const int row = wr*64 + m*16 + lcol;
        const int s = (kk*4 + lrow) ^ (row & 6);
        af[m] = *(const long*)&lds[bb + row*64 + s*8];
      }
      #pragma unroll
      for (int n = 0; n < 4; ++n) {
        const int row = wc*64 + n*16 + lcol;
        const int s = (kk*4 + lrow) ^ (row & 6);
        bfr[n] = *(const long*)&lds[bb + 8192 + row*64 + s*8];
      }
      #pragma unroll
      for (int m = 0; m < 4; ++m)
        #pragma unroll
        for (int n = 0; n < 4; ++n)
          acc[m][n] = __builtin_amdgcn_mfma_f32_16x16x32_fp8_fp8(af[m], bfr[n], acc[m][n], 0, 0, 0);
    }
    // Seal all waves' reads of this buf, then refill it with tile t+2.
    SBAR;
    if (t + 2 < NT) {
      STAGE2(t + 2);
      // Outstanding: t+1's 4 + t+2's 4. Wait t+1 resident; keep t+2 in flight.
      asm volatile("s_waitcnt vmcnt(4)" ::: "memory");
    } else {
      asm volatile("s_waitcnt vmcnt(0)" ::: "memory");
    }
    SBAR;
  }

  // ---- Epilogue: e = exp(acc * EPI_SCALE); row/col partial sums -> atomics ----
  // C/D mapping (dtype-independent): col = lane&15, row = (lane>>4)*4 + reg
  float rowsum[4][4];
  float colsum[4];
  #pragma unroll
  for (int m = 0; m < 4; ++m)
    #pragma unroll
    for (int r = 0; r < 4; ++r) rowsum[m][r] = 0.f;
  #pragma unroll
  for (int n = 0; n < 4; ++n) {
    float cs = 0.f;
    #pragma unroll
    for (int m = 0; m < 4; ++m)
      #pragma unroll
      for (int r = 0; r < 4; ++r) {
        const float e = __expf(acc[m][n][r] * EPI_SCALE);
        rowsum[m][r] += e;
        cs += e;
      }
    colsum[n] = cs;
  }
  #pragma unroll
  for (int m = 0; m < 4; ++m)
    #pragma unroll
    for (int r = 0; r < 4; ++r) {
      float v = rowsum[m][r];
      v += __shfl_xor(v, 1, 64);
      v += __shfl_xor(v, 2, 64);
      v += __shfl_xor(v, 4, 64);
      v += __shfl_xor(v, 8, 64);
      if (lcol == 0)
        atomicAdd(&Srow[brow*128 + wr*64 + m*16 + lrow*4 + r], v);
    }
  #pragma unroll
  for (int n = 0; n < 4; ++n) {
    float v = colsum[n];
    v += __shfl_xor(v, 16, 64);
    v += __shfl_xor(v, 32, 64);
    if (lane < 16)
      atomicAdd(&Scol[bcol*128 + wc*64 + n*16 + lcol], v);
  }
}

// ---------------- Kernel 3: loss = mean(0.5*(log Srow + log Scol) - diag) ----------------
__global__ __launch_bounds__(256) void loss_kernel(
    const float* __restrict__ Srow, const float* __restrict__ Scol,
    const float* __restrict__ diag, float* __restrict__ out, int B)
{
  float s = 0.f;
  for (int i = threadIdx.x; i < B; i += 256)
    s += 0.5f * (__logf(Srow[i]) + __logf(Scol[i])) - diag[i];
  #pragma unroll
  for (int m = 1; m < 64; m <<= 1) s += __shfl_xor(s, m, 64);
  __shared__ float red[4];
  if ((threadIdx.x & 63) == 0) red[threadIdx.x >> 6] = s;
  __syncthreads();
  if (threadIdx.x == 0) out[0] = (red[0] + red[1] + red[2] + red[3]) / (float)B;
}

extern "C" void kernel_launch(void* const* d_in, const int* in_sizes, int n_in,
                              void* d_out, int out_size, void* d_ws, size_t ws_size,
                              hipStream_t stream) {
  const float* A = (const float*)d_in[0];
  const float* T = (const float*)d_in[1];
  const int B = in_sizes[0] / D_DIM;     // 8192
  const int nbc = B / 128;               // 64

  char* ws = (char*)d_ws;
  unsigned char* An = (unsigned char*)ws;                       // B*D fp8 = 8 MB
  unsigned char* Tn = An + (size_t)B * D_DIM;                   // 8 MB
  float* Srow = (float*)(ws + (size_t)2 * B * D_DIM);
  float* Scol = Srow + B;
  float* diag = Scol + B;

  hipMemsetAsync(Srow, 0, (size_t)2 * B * sizeof(float), stream);
  norm_diag_kernel<<<B, 256, 0, stream>>>(A, T, (unsigned int*)An, (unsigned int*)Tn, diag);
  gemm_lse_kernel<<<nbc * nbc, 256, 0, stream>>>(An, Tn, Srow, Scol, nbc);
  loss_kernel<<<1, 256, 0, stream>>>(Srow, Scol, diag, (float*)d_out, B);
}